// Round 21
// baseline (3392.229 us; speedup 1.0000x reference)
//
#include <hip/hip_runtime.h>

// B=256, T=1024, H=512, IN=OUT=2
// Fused kernel, wave-specialized tail (R20 structure, chunk-index FIXED):
// per step, waves 0-1 compute the correction scan for their batch row
// (t=s-1) while waves 2-3 perform the ENTIRE 7-peer consume (2 chunks/thread,
// two sequential volleys) — corr overlaps the poll latency. Corr weights
// staged TRANSPOSED (lane-major): the row swizzle CANCELS on read, so lane
// holds cols lane*8..+7 -> weight index is [k][lane] (R20 bug: used off>>4).
// Everything else = R16/R19: 16 groups x 8 parts, 256 thr, 256 VGPR,
// W_hh register-resident, atomic-swap publish, single end-of-step barrier.

typedef short bf16x8 __attribute__((ext_vector_type(8)));
typedef float f32x4  __attribute__((ext_vector_type(4)));
typedef unsigned u32x2 __attribute__((ext_vector_type(2)));
typedef unsigned u32x4 __attribute__((ext_vector_type(4)));

__device__ __forceinline__ unsigned f2bf(float f) {
  unsigned u = __builtin_bit_cast(unsigned, f);
  return (u + 0x7fffu + ((u >> 16) & 1u)) >> 16;   // RTNE fp32->bf16
}
__device__ __forceinline__ float bf2f(unsigned short u) {
  unsigned v = (unsigned)u << 16;
  return __builtin_bit_cast(float, v);
}

#define KSTEP(kt, areg) \
  acc0 = __builtin_amdgcn_mfma_f32_16x16x32_bf16(areg, wf0[kt], acc0, 0, 0, 0); \
  acc1 = __builtin_amdgcn_mfma_f32_16x16x32_bf16(areg, wf1[kt], acc1, 0, 0, 0); \
  acc2 = __builtin_amdgcn_mfma_f32_16x16x32_bf16(areg, wf2[kt], acc2, 0, 0, 0);

#define PUBA(off, val) \
  asm volatile("global_atomic_swap_x2 %0, %1, off offset:" #off " sc1" \
               :: "v"(pp), "v"(val) : "memory")

__global__ void __launch_bounds__(256, 1) gru_fused(
    const float* __restrict__ V, const float* __restrict__ W_ih,
    const float* __restrict__ W_hh, const float* __restrict__ b_ih,
    const float* __restrict__ b_hh, const float* __restrict__ Wr,
    const float* __restrict__ Wa1, const float* __restrict__ ba1,
    const float* __restrict__ Wa2, const float* __restrict__ ba2v,
    const float* __restrict__ brv, const float* __restrict__ X0,
    float* __restrict__ out,         // [B][T][2]
    char* __restrict__ hbuf)         // [2 slots][16 g][8 p] x 4KB (512x8B units)
{
  const int tid  = threadIdx.x;
  const int w    = tid >> 6;          // wave 0..3 -> 16-col block
  const int lane = tid & 63;
  const int cl   = lane & 15;
  const int hi4  = lane >> 4;
  const int g    = blockIdx.x & 15;   // batch group; all 8 parts share bid%8
  const int p    = (blockIdx.x >> 4) & 7;   // col part (64 cols)

  __shared__ short hs[2][16][512];    // 32KB: [parity][row][col], swizzled
  __shared__ float wrt[2][8][64];     // 4KB  Wr transposed (lane-major)
  __shared__ float wa1t[4][4][64];    // 4KB  Wa1 transposed
  __shared__ float ba1t[4][64];       // 1KB
  __shared__ float wa2t[2][4][64];    // 2KB
  char* lds = (char*)hs;

  const int c = p * 64 + w * 16 + cl; // owned global h col

  // ---- pointwise constants ----
  const float wir0 = W_ih[c * 2 + 0],          wir1 = W_ih[c * 2 + 1];
  const float wiz0 = W_ih[(512 + c) * 2 + 0],  wiz1 = W_ih[(512 + c) * 2 + 1];
  const float win0 = W_ih[(1024 + c) * 2 + 0], win1 = W_ih[(1024 + c) * 2 + 1];
  const float bsr = b_ih[c] + b_hh[c];
  const float bsz = b_ih[512 + c] + b_hh[512 + c];
  const float bin = b_ih[1024 + c];
  const float bhn = b_hh[1024 + c];

  // attention scalars (wave-uniform)
  const float ba2_0 = ba2v[0], ba2_1 = ba2v[1];
  const float br0 = brv[0], br1 = brv[1];

  // ---- B-fragments: 3 gates x 16 k-tiles, register-resident (192 VGPRs) ----
  bf16x8 wf0[16], wf1[16], wf2[16];
  #pragma unroll
  for (int gt = 0; gt < 3; ++gt) {
    const float* src = W_hh + ((size_t)(gt * 512 + c)) * 512 + hi4 * 8;
    #pragma unroll
    for (int kt = 0; kt < 16; ++kt) {
      float4 x = *reinterpret_cast<const float4*>(src + kt * 32);
      float4 y = *reinterpret_cast<const float4*>(src + kt * 32 + 4);
      bf16x8 t;
      t[0] = (short)f2bf(x.x); t[1] = (short)f2bf(x.y);
      t[2] = (short)f2bf(x.z); t[3] = (short)f2bf(x.w);
      t[4] = (short)f2bf(y.x); t[5] = (short)f2bf(y.y);
      t[6] = (short)f2bf(y.z); t[7] = (short)f2bf(y.w);
      if (gt == 0) wf0[kt] = t; else if (gt == 1) wf1[kt] = t; else wf2[kt] = t;
    }
  }

  // zero h buffer 0; stage corr weights TRANSPOSED (lane-major)
  for (int i = tid; i < 8192; i += 256) ((unsigned*)lds)[i] = 0;
  for (int i = tid; i < 512; i += 256) {
    wrt[0][i & 7][i >> 3] = Wr[i];          // wrt[o][k][lane] = Wr[o*512+lane*8+k]
    wrt[1][i & 7][i >> 3] = Wr[512 + i];
  }
  for (int i = tid; i < 1024; i += 256) {
    // i = (lane*4+q)*4 + cc  ->  wa1t[q][cc][lane]
    wa1t[(i >> 2) & 3][i & 3][i >> 4] = Wa1[i];
  }
  if (tid < 256) {
    ba1t[tid & 3][tid >> 2]    = ba1[tid];
    wa2t[0][tid & 3][tid >> 2] = Wa2[tid];
    wa2t[1][tid & 3][tid >> 2] = Wa2[256 + tid];
  }
  __syncthreads();

  float h[4] = {0.f, 0.f, 0.f, 0.f};

  // correction x-state (waves 0,1: one batch row each)
  float x0 = 0.f, x1 = 0.f;
  if (w < 2) {
    const int gr = g * 16 + 2 * p + w;
    x0 = X0[gr * 2 + 0];
    x1 = X0[gr * 2 + 1];
  }

  // corr(t = sl-1) from full h(sl-1) in buffer[sl&1]; waves 0,1 only
  auto corr = [&](int sl) {
    const int row = 2 * p + w;
    const int gr  = g * 16 + row;
    const int t   = sl - 1;
    const char* hb = lds + (sl & 1) * 16384 + row * 1024;
    const unsigned off = ((unsigned)(lane * 16)) ^ (((unsigned)row & 7) << 4);
    bf16x8 hv = *(const bf16x8*)(hb + off);
    // swizzle cancels on read: these 16 bytes ARE columns lane*8..lane*8+7
    float r0 = 0.f, r1 = 0.f;
    #pragma unroll
    for (int k2 = 0; k2 < 8; ++k2) {
      float hf = bf2f((unsigned short)hv[k2]);
      r0 += wrt[0][k2][lane] * hf;
      r1 += wrt[1][k2][lane] * hf;
    }
    const float2 vt = *reinterpret_cast<const float2*>(&V[((size_t)gr * 1024 + t) * 2]);
    float l0 = 0.f, l1 = 0.f;
    #pragma unroll
    for (int q = 0; q < 4; ++q) {
      float hq = wa1t[q][0][lane] * x0 + wa1t[q][1][lane] * x1 +
                 wa1t[q][2][lane] * vt.x + wa1t[q][3][lane] * vt.y + ba1t[q][lane];
      hq = fmaxf(hq, 0.f);
      l0 += wa2t[0][q][lane] * hq;
      l1 += wa2t[1][q][lane] * hq;
    }
    #pragma unroll
    for (int m = 1; m < 64; m <<= 1) {
      r0 += __shfl_xor(r0, m); r1 += __shfl_xor(r1, m);
      l0 += __shfl_xor(l0, m); l1 += __shfl_xor(l1, m);
    }
    l0 += ba2_0; l1 += ba2_1;
    const float mx = fmaxf(l0, l1);
    const float e0 = __expf(l0 - mx), e1 = __expf(l1 - mx);
    const float inv = 1.f / (e0 + e1);
    x0 += vt.x + (e0 * inv) * (r0 + br0);
    x1 += vt.y + (e1 * inv) * (r1 + br1);
    if (lane == 0) {
      float2 o; o.x = x0; o.y = x1;
      *reinterpret_cast<float2*>(&out[((size_t)gr * 1024 + t) * 2]) = o;
    }
  };

  for (int s = 0; s < 1024; ++s) {
    // V loads issued early (complete under MFMA)
    float2 vv[4];
    #pragma unroll
    for (int j = 0; j < 4; ++j)
      vv[j] = *reinterpret_cast<const float2*>(
          &V[((size_t)(g * 16 + hi4 * 4 + j) * 1024 + (size_t)s) * 2]);

    f32x4 acc0 = {0.f,0.f,0.f,0.f}, acc1 = {0.f,0.f,0.f,0.f}, acc2 = {0.f,0.f,0.f,0.f};
    if (s > 0) {
      const char* ab = lds + (s & 1) * 16384 + cl * 1024;
      const unsigned sw = (unsigned)((cl & 7) << 4);
      #pragma unroll
      for (int kb = 0; kb < 4; ++kb) {
        bf16x8 a0 = *(const bf16x8*)(ab + (((kb * 4 + 0) * 64 + hi4 * 16) ^ sw));
        bf16x8 a1 = *(const bf16x8*)(ab + (((kb * 4 + 1) * 64 + hi4 * 16) ^ sw));
        bf16x8 a2 = *(const bf16x8*)(ab + (((kb * 4 + 2) * 64 + hi4 * 16) ^ sw));
        bf16x8 a3 = *(const bf16x8*)(ab + (((kb * 4 + 3) * 64 + hi4 * 16) ^ sw));
        KSTEP(kb * 4 + 0, a0) KSTEP(kb * 4 + 1, a1)
        KSTEP(kb * 4 + 2, a2) KSTEP(kb * 4 + 3, a3)
      }
    }

    // ---- pointwise GRU update: lane owns col c, rows hi4*4+{0..3} ----
    float hn_[4];
    #pragma unroll
    for (int j = 0; j < 4; ++j) {
      float pr = acc0[j] + bsr + wir0 * vv[j].x + wir1 * vv[j].y;
      float pz = acc1[j] + bsz + wiz0 * vv[j].x + wiz1 * vv[j].y;
      float rg = 1.f / (1.f + __expf(-pr));
      float zg = 1.f / (1.f + __expf(-pz));
      float pn = win0 * vv[j].x + win1 * vv[j].y + bin + rg * (acc2[j] + bhn);
      pn = fminf(fmaxf(pn, -30.f), 30.f);
      float e2 = __expf(2.f * pn);
      float tg = (e2 - 1.f) / (e2 + 1.f);
      hn_[j] = (1.f - zg) * tg + zg * h[j];
      h[j] = hn_[j];
    }

    // pack col pairs (even cl: cols c,c+1)
    unsigned pk[4];
    #pragma unroll
    for (int j = 0; j < 4; ++j) {
      float o = __shfl_xor(hn_[j], 1);
      pk[j] = f2bf(hn_[j]) | (f2bf(o) << 16);
    }

    // ---- publish: one 8B atomic-swap per (row, col-pair) — MALL-immediate ----
    if (!(cl & 1)) {
      char* pp = hbuf + (size_t)(s & 1) * 524288 + (size_t)(g * 8 + p) * 4096
               + (unsigned)(hi4 * 4) * 256u + (unsigned)((w * 16 + cl) >> 1) * 8u;
      u32x2 v0, v1, v2, v3;
      v0.x = pk[0]; v0.y = (unsigned)(s + 1);
      v1.x = pk[1]; v1.y = (unsigned)(s + 1);
      v2.x = pk[2]; v2.y = (unsigned)(s + 1);
      v3.x = pk[3]; v3.y = (unsigned)(s + 1);
      PUBA(0, v0); PUBA(256, v1); PUBA(512, v2); PUBA(768, v3);
    }

    // ---- own cols -> LDS next-parity buffer ----
    if (!(cl & 1)) {
      char* wb = lds + ((s + 1) & 1) * 16384;
      const unsigned bc = (unsigned)(2 * c);
      #pragma unroll
      for (int j = 0; j < 4; ++j) {
        const unsigned row = (unsigned)(hi4 * 4 + j);
        *(unsigned*)(wb + row * 1024 + (bc ^ ((row & 7) << 4))) = pk[j];
      }
    }

    // ---- wave-specialized tail: waves 0-1 corr; waves 2-3 full consume ----
    if (w < 2) {
      if (s > 0) corr(s);
    } else {
      char* wb = lds + ((s + 1) & 1) * 16384;
      const unsigned want = (unsigned)(s + 1);
      const char* slot = hbuf + (size_t)(s & 1) * 524288 + (size_t)(g * 8) * 4096;
      const int local = tid & 127;
      __builtin_amdgcn_s_sleep(8);   // preserve late-issue pacing (R14/R17)
      #define RP(r) ((p + (r) + 1) & 7)
      #pragma unroll
      for (int ci = 0; ci < 2; ++ci) {
        const int idx = local * 2 + ci;
        const int ur = idx >> 4, uc = idx & 15;
        const char* sbase = slot + (unsigned)(ur * 256 + uc * 16);
        u32x4 u0, u1, u2, u3, u4, u5, u6;
        unsigned pend = 0x7f;
        #define ISSUE(r, ureg) \
          if (pend & (1u << (r))) { \
            const char* src = sbase + RP(r) * 4096; \
            asm volatile("global_load_dwordx4 %0, %1, off sc1" \
                         : "=v"(ureg) : "v"(src) : "memory"); \
          }
        #define HARVEST(r, ureg) \
          if ((pend & (1u << (r))) && ureg.y == want && ureg.w == want) { \
            const unsigned bc = (unsigned)(RP(r) * 128 + uc * 8); \
            uint2 pay; pay.x = ureg.x; pay.y = ureg.z; \
            *(uint2*)(wb + (unsigned)ur * 1024 + \
                      (bc ^ (((unsigned)ur & 7) << 4))) = pay; \
            pend &= ~(1u << (r)); \
          }
        int gd = 0;
        while (pend) {
          ISSUE(0, u0) ISSUE(1, u1) ISSUE(2, u2) ISSUE(3, u3)
          ISSUE(4, u4) ISSUE(5, u5) ISSUE(6, u6)
          asm volatile("s_waitcnt vmcnt(0)" ::: "memory");
          HARVEST(0, u0) HARVEST(1, u1) HARVEST(2, u2) HARVEST(3, u3)
          HARVEST(4, u4) HARVEST(5, u5) HARVEST(6, u6)
          if (++gd > (1 << 14)) break;   // hang insurance -> fast wrong answer
        }
        #undef ISSUE
        #undef HARVEST
      }
      #undef RP
    }
    __syncthreads();   // single per-step barrier (LDS parity handoff)
  }

  // epilogue: correction for the final step (t=1023; full h(1023) in buffer 0)
  if (w < 2) corr(1024);
}

extern "C" void kernel_launch(void* const* d_in, const int* in_sizes, int n_in,
                              void* d_out, int out_size, void* d_ws, size_t ws_size,
                              hipStream_t stream) {
  const float* X0   = (const float*)d_in[0];
  const float* V    = (const float*)d_in[1];
  const float* W_ih = (const float*)d_in[2];
  const float* W_hh = (const float*)d_in[3];
  const float* b_ih = (const float*)d_in[4];
  const float* b_hh = (const float*)d_in[5];
  const float* Wa1  = (const float*)d_in[6];
  const float* ba1  = (const float*)d_in[7];
  const float* Wa2  = (const float*)d_in[8];
  const float* ba2  = (const float*)d_in[9];
  const float* Wr   = (const float*)d_in[10];
  const float* br   = (const float*)d_in[11];
  float* out = (float*)d_out;

  char* hbuf = (char*)d_ws;                       // 1 MB (2 slots x 512KB)
  hipMemsetAsync(hbuf, 0, 1024 * 1024, stream);

  hipLaunchKernelGGL(gru_fused, dim3(128), dim3(256), 0, stream,
                     V, W_ih, W_hh, b_ih, b_hh, Wr,
                     Wa1, ba1, Wa2, ba2, br, X0, out, hbuf);
}

// Round 22
// 3169.272 us; speedup vs baseline: 1.0703x; 1.0703x over previous
//
#include <hip/hip_runtime.h>

// B=256, T=1024, H=512, IN=OUT=2
// Fused kernel = R19 schedule (best: all-wave single-chunk consume; corr on
// waves 0-1 before consume) + R21's verified conflict-free TRANSPOSED corr
// weights (lane-major [k][lane]; swizzle cancels on read so lane holds cols
// lane*8..+7). 16 groups x 8 parts; 256 thr (4 waves, 256 VGPR); W_hh frags
// register-resident; atomic-swap publish (MALL-immediate); 7-peer volley +
// straggler retry (late-issued); single end-of-step barrier; phase 2 fused.

typedef short bf16x8 __attribute__((ext_vector_type(8)));
typedef float f32x4  __attribute__((ext_vector_type(4)));
typedef unsigned u32x2 __attribute__((ext_vector_type(2)));
typedef unsigned u32x4 __attribute__((ext_vector_type(4)));

__device__ __forceinline__ unsigned f2bf(float f) {
  unsigned u = __builtin_bit_cast(unsigned, f);
  return (u + 0x7fffu + ((u >> 16) & 1u)) >> 16;   // RTNE fp32->bf16
}
__device__ __forceinline__ float bf2f(unsigned short u) {
  unsigned v = (unsigned)u << 16;
  return __builtin_bit_cast(float, v);
}

#define KSTEP(kt, areg) \
  acc0 = __builtin_amdgcn_mfma_f32_16x16x32_bf16(areg, wf0[kt], acc0, 0, 0, 0); \
  acc1 = __builtin_amdgcn_mfma_f32_16x16x32_bf16(areg, wf1[kt], acc1, 0, 0, 0); \
  acc2 = __builtin_amdgcn_mfma_f32_16x16x32_bf16(areg, wf2[kt], acc2, 0, 0, 0);

#define PUBA(off, val) \
  asm volatile("global_atomic_swap_x2 %0, %1, off offset:" #off " sc1" \
               :: "v"(pp), "v"(val) : "memory")

__global__ void __launch_bounds__(256, 1) gru_fused(
    const float* __restrict__ V, const float* __restrict__ W_ih,
    const float* __restrict__ W_hh, const float* __restrict__ b_ih,
    const float* __restrict__ b_hh, const float* __restrict__ Wr,
    const float* __restrict__ Wa1, const float* __restrict__ ba1,
    const float* __restrict__ Wa2, const float* __restrict__ ba2v,
    const float* __restrict__ brv, const float* __restrict__ X0,
    float* __restrict__ out,         // [B][T][2]
    char* __restrict__ hbuf)         // [2 slots][16 g][8 p] x 4KB (512x8B units)
{
  const int tid  = threadIdx.x;
  const int w    = tid >> 6;          // wave 0..3 -> 16-col block
  const int lane = tid & 63;
  const int cl   = lane & 15;
  const int hi4  = lane >> 4;
  const int g    = blockIdx.x & 15;   // batch group; all 8 parts share bid%8
  const int p    = (blockIdx.x >> 4) & 7;   // col part (64 cols)

  __shared__ short hs[2][16][512];    // 32KB: [parity][row][col], swizzled
  __shared__ float wrt[2][8][64];     // 4KB  Wr transposed (lane-major)
  __shared__ float wa1t[4][4][64];    // 4KB  Wa1 transposed
  __shared__ float ba1t[4][64];       // 1KB
  __shared__ float wa2t[2][4][64];    // 2KB
  char* lds = (char*)hs;

  const int c = p * 64 + w * 16 + cl; // owned global h col

  // ---- pointwise constants ----
  const float wir0 = W_ih[c * 2 + 0],          wir1 = W_ih[c * 2 + 1];
  const float wiz0 = W_ih[(512 + c) * 2 + 0],  wiz1 = W_ih[(512 + c) * 2 + 1];
  const float win0 = W_ih[(1024 + c) * 2 + 0], win1 = W_ih[(1024 + c) * 2 + 1];
  const float bsr = b_ih[c] + b_hh[c];
  const float bsz = b_ih[512 + c] + b_hh[512 + c];
  const float bin = b_ih[1024 + c];
  const float bhn = b_hh[1024 + c];

  // attention scalars (wave-uniform)
  const float ba2_0 = ba2v[0], ba2_1 = ba2v[1];
  const float br0 = brv[0], br1 = brv[1];

  // ---- B-fragments: 3 gates x 16 k-tiles, register-resident (192 VGPRs) ----
  bf16x8 wf0[16], wf1[16], wf2[16];
  #pragma unroll
  for (int gt = 0; gt < 3; ++gt) {
    const float* src = W_hh + ((size_t)(gt * 512 + c)) * 512 + hi4 * 8;
    #pragma unroll
    for (int kt = 0; kt < 16; ++kt) {
      float4 x = *reinterpret_cast<const float4*>(src + kt * 32);
      float4 y = *reinterpret_cast<const float4*>(src + kt * 32 + 4);
      bf16x8 t;
      t[0] = (short)f2bf(x.x); t[1] = (short)f2bf(x.y);
      t[2] = (short)f2bf(x.z); t[3] = (short)f2bf(x.w);
      t[4] = (short)f2bf(y.x); t[5] = (short)f2bf(y.y);
      t[6] = (short)f2bf(y.z); t[7] = (short)f2bf(y.w);
      if (gt == 0) wf0[kt] = t; else if (gt == 1) wf1[kt] = t; else wf2[kt] = t;
    }
  }

  // zero h buffer 0; stage corr weights TRANSPOSED (lane-major)
  for (int i = tid; i < 8192; i += 256) ((unsigned*)lds)[i] = 0;
  for (int i = tid; i < 512; i += 256) {
    wrt[0][i & 7][i >> 3] = Wr[i];          // wrt[o][k][lane] = Wr[o*512+lane*8+k]
    wrt[1][i & 7][i >> 3] = Wr[512 + i];
  }
  for (int i = tid; i < 1024; i += 256) {
    // i = (lane*4+q)*4 + cc  ->  wa1t[q][cc][lane]
    wa1t[(i >> 2) & 3][i & 3][i >> 4] = Wa1[i];
  }
  if (tid < 256) {
    ba1t[tid & 3][tid >> 2]    = ba1[tid];
    wa2t[0][tid & 3][tid >> 2] = Wa2[tid];
    wa2t[1][tid & 3][tid >> 2] = Wa2[256 + tid];
  }
  __syncthreads();

  // consumer: thread (urow, ucol) reads 16B covering cols 4*ucol..+3 (2 units)
  const int urow = tid >> 4, ucol = tid & 15;
  const unsigned roff = (unsigned)(urow * 256 + ucol * 16);

  float h[4] = {0.f, 0.f, 0.f, 0.f};

  // correction x-state (waves 0,1: one batch row each)
  float x0 = 0.f, x1 = 0.f;
  if (w < 2) {
    const int gr = g * 16 + 2 * p + w;
    x0 = X0[gr * 2 + 0];
    x1 = X0[gr * 2 + 1];
  }

  // corr(t = sl-1) from full h(sl-1) in buffer[sl&1]; waves 0,1 only
  auto corr = [&](int sl) {
    const int row = 2 * p + w;
    const int gr  = g * 16 + row;
    const int t   = sl - 1;
    const char* hb = lds + (sl & 1) * 16384 + row * 1024;
    const unsigned off = ((unsigned)(lane * 16)) ^ (((unsigned)row & 7) << 4);
    bf16x8 hv = *(const bf16x8*)(hb + off);
    // swizzle cancels on read: these 16 bytes ARE columns lane*8..lane*8+7
    float r0 = 0.f, r1 = 0.f;
    #pragma unroll
    for (int k2 = 0; k2 < 8; ++k2) {
      float hf = bf2f((unsigned short)hv[k2]);
      r0 += wrt[0][k2][lane] * hf;
      r1 += wrt[1][k2][lane] * hf;
    }
    const float2 vt = *reinterpret_cast<const float2*>(&V[((size_t)gr * 1024 + t) * 2]);
    float l0 = 0.f, l1 = 0.f;
    #pragma unroll
    for (int q = 0; q < 4; ++q) {
      float hq = wa1t[q][0][lane] * x0 + wa1t[q][1][lane] * x1 +
                 wa1t[q][2][lane] * vt.x + wa1t[q][3][lane] * vt.y + ba1t[q][lane];
      hq = fmaxf(hq, 0.f);
      l0 += wa2t[0][q][lane] * hq;
      l1 += wa2t[1][q][lane] * hq;
    }
    #pragma unroll
    for (int m = 1; m < 64; m <<= 1) {
      r0 += __shfl_xor(r0, m); r1 += __shfl_xor(r1, m);
      l0 += __shfl_xor(l0, m); l1 += __shfl_xor(l1, m);
    }
    l0 += ba2_0; l1 += ba2_1;
    const float mx = fmaxf(l0, l1);
    const float e0 = __expf(l0 - mx), e1 = __expf(l1 - mx);
    const float inv = 1.f / (e0 + e1);
    x0 += vt.x + (e0 * inv) * (r0 + br0);
    x1 += vt.y + (e1 * inv) * (r1 + br1);
    if (lane == 0) {
      float2 o; o.x = x0; o.y = x1;
      *reinterpret_cast<float2*>(&out[((size_t)gr * 1024 + t) * 2]) = o;
    }
  };

  for (int s = 0; s < 1024; ++s) {
    // V loads issued early (complete under MFMA)
    float2 vv[4];
    #pragma unroll
    for (int j = 0; j < 4; ++j)
      vv[j] = *reinterpret_cast<const float2*>(
          &V[((size_t)(g * 16 + hi4 * 4 + j) * 1024 + (size_t)s) * 2]);

    f32x4 acc0 = {0.f,0.f,0.f,0.f}, acc1 = {0.f,0.f,0.f,0.f}, acc2 = {0.f,0.f,0.f,0.f};
    if (s > 0) {
      const char* ab = lds + (s & 1) * 16384 + cl * 1024;
      const unsigned sw = (unsigned)((cl & 7) << 4);
      #pragma unroll
      for (int kb = 0; kb < 4; ++kb) {
        bf16x8 a0 = *(const bf16x8*)(ab + (((kb * 4 + 0) * 64 + hi4 * 16) ^ sw));
        bf16x8 a1 = *(const bf16x8*)(ab + (((kb * 4 + 1) * 64 + hi4 * 16) ^ sw));
        bf16x8 a2 = *(const bf16x8*)(ab + (((kb * 4 + 2) * 64 + hi4 * 16) ^ sw));
        bf16x8 a3 = *(const bf16x8*)(ab + (((kb * 4 + 3) * 64 + hi4 * 16) ^ sw));
        KSTEP(kb * 4 + 0, a0) KSTEP(kb * 4 + 1, a1)
        KSTEP(kb * 4 + 2, a2) KSTEP(kb * 4 + 3, a3)
      }
    }

    // ---- pointwise GRU update: lane owns col c, rows hi4*4+{0..3} ----
    float hn_[4];
    #pragma unroll
    for (int j = 0; j < 4; ++j) {
      float pr = acc0[j] + bsr + wir0 * vv[j].x + wir1 * vv[j].y;
      float pz = acc1[j] + bsz + wiz0 * vv[j].x + wiz1 * vv[j].y;
      float rg = 1.f / (1.f + __expf(-pr));
      float zg = 1.f / (1.f + __expf(-pz));
      float pn = win0 * vv[j].x + win1 * vv[j].y + bin + rg * (acc2[j] + bhn);
      pn = fminf(fmaxf(pn, -30.f), 30.f);
      float e2 = __expf(2.f * pn);
      float tg = (e2 - 1.f) / (e2 + 1.f);
      hn_[j] = (1.f - zg) * tg + zg * h[j];
      h[j] = hn_[j];
    }

    // pack col pairs (even cl: cols c,c+1)
    unsigned pk[4];
    #pragma unroll
    for (int j = 0; j < 4; ++j) {
      float o = __shfl_xor(hn_[j], 1);
      pk[j] = f2bf(hn_[j]) | (f2bf(o) << 16);
    }

    // ---- publish: one 8B atomic-swap per (row, col-pair) — MALL-immediate ----
    if (!(cl & 1)) {
      char* pp = hbuf + (size_t)(s & 1) * 524288 + (size_t)(g * 8 + p) * 4096
               + (unsigned)(hi4 * 4) * 256u + (unsigned)((w * 16 + cl) >> 1) * 8u;
      u32x2 v0, v1, v2, v3;
      v0.x = pk[0]; v0.y = (unsigned)(s + 1);
      v1.x = pk[1]; v1.y = (unsigned)(s + 1);
      v2.x = pk[2]; v2.y = (unsigned)(s + 1);
      v3.x = pk[3]; v3.y = (unsigned)(s + 1);
      PUBA(0, v0); PUBA(256, v1); PUBA(512, v2); PUBA(768, v3);
    }

    // ---- own cols -> LDS next-parity buffer ----
    if (!(cl & 1)) {
      char* wb = lds + ((s + 1) & 1) * 16384;
      const unsigned bc = (unsigned)(2 * c);
      #pragma unroll
      for (int j = 0; j < 4; ++j) {
        const unsigned row = (unsigned)(hi4 * 4 + j);
        *(unsigned*)(wb + row * 1024 + (bc ^ ((row & 7) << 4))) = pk[j];
      }
    }

    // ---- correction for t=s-1 (waves 0,1; conflict-free weights) ----
    if (s > 0 && w < 2) corr(s);

    // ---- consume 7 peer parts' h(s) (all waves, single chunk/thread) ----
    {
      char* wb = lds + ((s + 1) & 1) * 16384;
      const unsigned want = (unsigned)(s + 1);
      const char* sbase = hbuf + (size_t)(s & 1) * 524288 + (size_t)(g * 8) * 4096 + roff;
      u32x4 u0, u1, u2, u3, u4, u5, u6;
      unsigned pend = 0x7f;
      if (w >= 2) __builtin_amdgcn_s_sleep(8);   // preserve late-issue pacing
      #define RP(r) ((p + (r) + 1) & 7)
      #define ISSUE(r, ureg) \
        if (pend & (1u << (r))) { \
          const char* src = sbase + RP(r) * 4096; \
          asm volatile("global_load_dwordx4 %0, %1, off sc1" \
                       : "=v"(ureg) : "v"(src) : "memory"); \
        }
      #define HARVEST(r, ureg) \
        if ((pend & (1u << (r))) && ureg.y == want && ureg.w == want) { \
          const unsigned bc = (unsigned)(RP(r) * 128 + ucol * 8); \
          uint2 pay; pay.x = ureg.x; pay.y = ureg.z; \
          *(uint2*)(wb + (unsigned)urow * 1024 + \
                    (bc ^ (((unsigned)urow & 7) << 4))) = pay; \
          pend &= ~(1u << (r)); \
        }
      int gd = 0;
      while (pend) {
        ISSUE(0, u0) ISSUE(1, u1) ISSUE(2, u2) ISSUE(3, u3)
        ISSUE(4, u4) ISSUE(5, u5) ISSUE(6, u6)
        asm volatile("s_waitcnt vmcnt(0)" ::: "memory");
        HARVEST(0, u0) HARVEST(1, u1) HARVEST(2, u2) HARVEST(3, u3)
        HARVEST(4, u4) HARVEST(5, u5) HARVEST(6, u6)
        if (++gd > (1 << 14)) break;   // hang insurance -> fast wrong answer
      }
      #undef RP
      #undef ISSUE
      #undef HARVEST
    }
    __syncthreads();   // single per-step barrier (LDS parity handoff)
  }

  // epilogue: correction for the final step (t=1023; full h(1023) in buffer 0)
  if (w < 2) corr(1024);
}

extern "C" void kernel_launch(void* const* d_in, const int* in_sizes, int n_in,
                              void* d_out, int out_size, void* d_ws, size_t ws_size,
                              hipStream_t stream) {
  const float* X0   = (const float*)d_in[0];
  const float* V    = (const float*)d_in[1];
  const float* W_ih = (const float*)d_in[2];
  const float* W_hh = (const float*)d_in[3];
  const float* b_ih = (const float*)d_in[4];
  const float* b_hh = (const float*)d_in[5];
  const float* Wa1  = (const float*)d_in[6];
  const float* ba1  = (const float*)d_in[7];
  const float* Wa2  = (const float*)d_in[8];
  const float* ba2  = (const float*)d_in[9];
  const float* Wr   = (const float*)d_in[10];
  const float* br   = (const float*)d_in[11];
  float* out = (float*)d_out;

  char* hbuf = (char*)d_ws;                       // 1 MB (2 slots x 512KB)
  hipMemsetAsync(hbuf, 0, 1024 * 1024, stream);

  hipLaunchKernelGGL(gru_fused, dim3(128), dim3(256), 0, stream,
                     V, W_ih, W_hh, b_ih, b_hh, Wr,
                     Wa1, ba1, Wa2, ba2, br, X0, out, hbuf);
}